// Round 9
// baseline (330.050 us; speedup 1.0000x reference)
//
#include <hip/hip_runtime.h>
#include <math.h>

#define N_  32
#define T_  8192
#define D_  64
#define K_  64
#define CHUNKS 32
#define TOK_PER_BLOCK (T_ / CHUNKS)    // 256
#define TB 64                          // tokens per batch
#define NBATCH (TOK_PER_BLOCK / TB)    // 4
#define STATS_PER_N (K_ + 2 * K_ * D_) // 8256
#define XSTR 72                        // f16 stride for Xs/Pt rows

typedef _Float16 half_t;
typedef __attribute__((ext_vector_type(8)))  _Float16 v8h;
typedef __attribute__((ext_vector_type(4)))  float    v4f;
typedef __attribute__((ext_vector_type(16))) float    v16f;

// agent-scope (device) atomics: stores/loads go to the coherence point,
// bypassing the non-coherent per-XCD L2 (G16) — required for the
// same-kernel producer->consumer hand-off of the partial records.
__device__ __forceinline__ void st_agent(float* p, float v) {
    __hip_atomic_store(p, v, __ATOMIC_RELAXED, __HIP_MEMORY_SCOPE_AGENT);
}
__device__ __forceinline__ float ld_agent(const float* p) {
    return __hip_atomic_load(p, __ATOMIC_RELAXED, __HIP_MEMORY_SCOPE_AGENT);
}

// ---------------------------------------------------------------------------
// prep (grid 9): blocks 0..7 pack WH (f16 MFMA A-frag order);
// block 8: Ap[k] = 2 log w - 0.5*sum_d(log c + mu^2/c), zero flags[32].
// ---------------------------------------------------------------------------
__global__ void prep_kernel(const float* __restrict__ w, const float* __restrict__ mu,
                            const float* __restrict__ cv, float* __restrict__ Ap,
                            half_t* __restrict__ WH, int* __restrict__ flags) {
    if (blockIdx.x < 8) {
#pragma unroll
        for (int i = 0; i < 4; ++i) {
            const int e = blockIdx.x * 1024 + i * 256 + threadIdx.x;  // 0..8191
            const int j = e & 7, l = (e >> 3) & 63, fs = e >> 9;
            const int tile = fs >> 2, s = fs & 3;
            const int kc = 16 * tile + (l & 15);
            const int f  = 32 * s + 8 * (l >> 4) + j;
            float val;
            if (f < 64) val = mu[kc * 64 + f] / cv[kc * 64 + f];
            else        val = -0.5f / cv[kc * 64 + (f - 64)];
            WH[e] = (half_t)val;
        }
    } else {
        if (threadIdx.x < 32) flags[threadIdx.x] = 0;
        if (threadIdx.x < K_) {
            const int k = threadIdx.x;
            float acc = 0.f;
            for (int d = 0; d < D_; ++d) {
                const int idx = k * D_ + d;
                const float c = cv[idx], m = mu[idx];
                acc += logf(c) + m * m / c;
            }
            Ap[k] = 2.f * logf(w[k]) - 0.5f * acc;
        }
    }
}

// ---------------------------------------------------------------------------
// main: grid (32, 32) = 1024 blocks, block 256 (4 waves).
// Per batch: Phase A builds MFMA B-frags directly from global->registers
// (no LDS reads in A), stages Xs only (Qs dropped: Phase B squares f16
// in-register for the s2 waves). Phase B mfma 32x32x16 from Xs/Pt.
// Flush (mode 1): agent-scope stores of the block's partial record; the
// LAST block per n (device-scope counter) finalizes n inline: chunk-sum,
// v0/v1/v2 transform + signed sqrt, L2 norm, writes out.
// ---------------------------------------------------------------------------
__launch_bounds__(256, 3)
__global__ void main_kernel(const float* __restrict__ x, const float* __restrict__ Ap,
                            const half_t* __restrict__ WH, float* __restrict__ outbuf,
                            float* __restrict__ out, int* __restrict__ flags,
                            const float* __restrict__ w, const float* __restrict__ mu,
                            const float* __restrict__ cv, int mode) {
    __shared__ union {
        struct {                       // main-loop phase (19.5 KB)
            half_t Xs[TB][XSTR];
            half_t Pt[K_][XSTR];
            float  s0sh[4][64];
        } m;
        struct {                       // finalize phase (re-uses the same LDS)
            float s0f[64];
            float red[4];
            int   lastflag;
        } f;
    } sm;

    const int tid  = threadIdx.x;
    const int lane = tid & 63;
    const int wv   = tid >> 6;
    const int chunk = blockIdx.x;
    const int n     = blockIdx.y;
    const int q     = lane >> 4;
    const int c0    = lane & 15;
    const int tok   = 16 * wv + c0;   // this lane's token within the batch

    // resident weight A-frags
    v8h Wf[16];
#pragma unroll
    for (int t = 0; t < 4; ++t)
#pragma unroll
        for (int s = 0; s < 4; ++s)
            Wf[t * 4 + s] = *(const v8h*)(WH + (size_t)((t * 4 + s) * 64 + lane) * 8);

    float apv[16];
#pragma unroll
    for (int t = 0; t < 4; ++t)
#pragma unroll
        for (int r = 0; r < 4; ++r) apv[t * 4 + r] = Ap[16 * t + 4 * q + r];

    float S0loc[16];
#pragma unroll
    for (int j = 0; j < 16; ++j) S0loc[j] = 0.f;

    const int sig = wv >> 1;   // 0: s1 (B = x), 1: s2 (B = x^2, squared in-reg)
    const int dh  = wv & 1;    // d-half
    v16f accB[2];
#pragma unroll
    for (int m = 0; m < 2; ++m)
#pragma unroll
        for (int r = 0; r < 16; ++r) accB[m][r] = 0.f;

    const size_t xbase = ((size_t)n * T_ + (size_t)chunk * TOK_PER_BLOCK) * (size_t)D_;
    const float* xrow0 = x + xbase + tok * 64 + 8 * q;

    // preload batch 0
    float4 R[4];
    R[0] = *(const float4*)(xrow0);
    R[1] = *(const float4*)(xrow0 + 4);
    R[2] = *(const float4*)(xrow0 + 32);
    R[3] = *(const float4*)(xrow0 + 36);

#pragma unroll 1
    for (int batch = 0; batch < NBATCH; ++batch) {
        // ---- convert current R -> frags (registers), stage x to LDS for B ----
        v8h xh0, xh1, qh0, qh1;
        {
            const float4 a = R[0], b = R[1], c = R[2], d = R[3];
            xh0[0] = (half_t)a.x; xh0[1] = (half_t)a.y; xh0[2] = (half_t)a.z; xh0[3] = (half_t)a.w;
            xh0[4] = (half_t)b.x; xh0[5] = (half_t)b.y; xh0[6] = (half_t)b.z; xh0[7] = (half_t)b.w;
            xh1[0] = (half_t)c.x; xh1[1] = (half_t)c.y; xh1[2] = (half_t)c.z; xh1[3] = (half_t)c.w;
            xh1[4] = (half_t)d.x; xh1[5] = (half_t)d.y; xh1[6] = (half_t)d.z; xh1[7] = (half_t)d.w;
            qh0[0] = (half_t)(a.x * a.x); qh0[1] = (half_t)(a.y * a.y);
            qh0[2] = (half_t)(a.z * a.z); qh0[3] = (half_t)(a.w * a.w);
            qh0[4] = (half_t)(b.x * b.x); qh0[5] = (half_t)(b.y * b.y);
            qh0[6] = (half_t)(b.z * b.z); qh0[7] = (half_t)(b.w * b.w);
            qh1[0] = (half_t)(c.x * c.x); qh1[1] = (half_t)(c.y * c.y);
            qh1[2] = (half_t)(c.z * c.z); qh1[3] = (half_t)(c.w * c.w);
            qh1[4] = (half_t)(d.x * d.x); qh1[5] = (half_t)(d.y * d.y);
            qh1[6] = (half_t)(d.z * d.z); qh1[7] = (half_t)(d.w * d.w);
            *(v8h*)&sm.m.Xs[tok][8 * q]      = xh0;
            *(v8h*)&sm.m.Xs[tok][32 + 8 * q] = xh1;
        }

        // ---- prefetch next batch ----
        if (batch + 1 < NBATCH) {
            const float* xr = xrow0 + (size_t)(batch + 1) * TB * D_;
            R[0] = *(const float4*)(xr);
            R[1] = *(const float4*)(xr + 4);
            R[2] = *(const float4*)(xr + 32);
            R[3] = *(const float4*)(xr + 36);
        }

        // ---------------- Phase A (register frags only) ----------------
        {
            v4f acc[4];
#pragma unroll
            for (int t = 0; t < 4; ++t) acc[t] = (v4f)(0.f);
#pragma unroll
            for (int t = 0; t < 4; ++t) {
                acc[t] = __builtin_amdgcn_mfma_f32_16x16x32_f16(Wf[t * 4 + 0], xh0, acc[t], 0, 0, 0);
                acc[t] = __builtin_amdgcn_mfma_f32_16x16x32_f16(Wf[t * 4 + 1], xh1, acc[t], 0, 0, 0);
                acc[t] = __builtin_amdgcn_mfma_f32_16x16x32_f16(Wf[t * 4 + 2], qh0, acc[t], 0, 0, 0);
                acc[t] = __builtin_amdgcn_mfma_f32_16x16x32_f16(Wf[t * 4 + 3], qh1, acc[t], 0, 0, 0);
            }
            float pv[16];
            float m = -1e30f;
#pragma unroll
            for (int t = 0; t < 4; ++t)
#pragma unroll
                for (int r = 0; r < 4; ++r) {
                    const float lg = acc[t][r] + apv[t * 4 + r];
                    pv[t * 4 + r] = lg;
                    m = fmaxf(m, lg);
                }
            m = fmaxf(m, __shfl_xor(m, 16, 64));
            m = fmaxf(m, __shfl_xor(m, 32, 64));
            float ssum = 0.f;
#pragma unroll
            for (int j = 0; j < 16; ++j) { pv[j] = __expf(pv[j] - m); ssum += pv[j]; }
            ssum += __shfl_xor(ssum, 16, 64);
            ssum += __shfl_xor(ssum, 32, 64);
            const float rs = 1.f / ssum;
#pragma unroll
            for (int j = 0; j < 16; ++j) { pv[j] *= rs; S0loc[j] += pv[j]; }
#pragma unroll
            for (int t = 0; t < 4; ++t)
#pragma unroll
                for (int r = 0; r < 4; ++r)
                    sm.m.Pt[16 * t + 4 * q + r][tok] = (half_t)pv[t * 4 + r];
        }
        __syncthreads();   // Xs/Pt visible

        // ---------------- Phase B ----------------
        {
            const int mm  = lane & 31;
            const int h   = lane >> 5;
            const int d   = 32 * dh + mm;
            const half_t* Arow0 = &sm.m.Pt[mm][0];
            const half_t* Arow1 = &sm.m.Pt[32 + mm][0];
#pragma unroll
            for (int st = 0; st < 4; ++st) {
                const int tB = 16 * st + 8 * h;
                const v8h a0 = *(const v8h*)(Arow0 + tB);
                const v8h a1 = *(const v8h*)(Arow1 + tB);
                v8h bf;
#pragma unroll
                for (int j = 0; j < 8; ++j)
                    bf[j] = sm.m.Xs[tB + j][d];
                if (sig) bf = bf * bf;   // s2 operand: square in f16 (4 pk_mul)
                accB[0] = __builtin_amdgcn_mfma_f32_32x32x16_f16(a0, bf, accB[0], 0, 0, 0);
                accB[1] = __builtin_amdgcn_mfma_f32_32x32x16_f16(a1, bf, accB[1], 0, 0, 0);
            }
        }
        __syncthreads();   // Phase B done -> LDS reusable next batch
    }

    // -------- s0 block reduce --------
#pragma unroll
    for (int j = 0; j < 16; ++j) {
        float v = S0loc[j];
        v += __shfl_xor(v, 1, 64);
        v += __shfl_xor(v, 2, 64);
        v += __shfl_xor(v, 4, 64);
        v += __shfl_xor(v, 8, 64);
        S0loc[j] = v;
    }
    if (c0 == 0) {
#pragma unroll
        for (int t = 0; t < 4; ++t)
#pragma unroll
            for (int r = 0; r < 4; ++r)
                sm.m.s0sh[wv][16 * t + 4 * q + r] = S0loc[t * 4 + r];
    }
    __syncthreads();

    if (mode == 1) {
        // -------- flush partial record (agent-scope stores) --------
        float* dstb = outbuf + (size_t)(n * CHUNKS + chunk) * STATS_PER_N;
        if (tid < 64)
            st_agent(&dstb[tid],
                     sm.m.s0sh[0][tid] + sm.m.s0sh[1][tid] + sm.m.s0sh[2][tid] + sm.m.s0sh[3][tid]);
        {
            const int d = 32 * dh + (lane & 31);
            float* dst = dstb + 64 + sig * 4096;
#pragma unroll
            for (int mt = 0; mt < 2; ++mt)
#pragma unroll
                for (int r = 0; r < 16; ++r) {
                    const int kc = 32 * mt + (r & 3) + 8 * (r >> 2) + 4 * (lane >> 5);
                    st_agent(&dst[kc * 64 + d], accB[mt][r]);
                }
        }
        __threadfence();           // release: record visible device-wide
        __syncthreads();
        if (tid == 0) {
            const int old = __hip_atomic_fetch_add(&flags[n], 1, __ATOMIC_ACQ_REL,
                                                   __HIP_MEMORY_SCOPE_AGENT);
            sm.f.lastflag = (old == CHUNKS - 1) ? 1 : 0;
        }
        __syncthreads();
        if (!sm.f.lastflag) return;
        __threadfence();           // acquire side

        // -------- finalize n (last-arriving block only) --------
        const float* Pn = outbuf + (size_t)n * CHUNKS * STATS_PER_N;
        if (tid < 64) {
            float a = 0.f;
#pragma unroll
            for (int c = 0; c < CHUNKS; ++c)
                a += ld_agent(Pn + (size_t)c * STATS_PER_N + tid);
            sm.f.s0f[tid] = a;
        }
        __syncthreads();

        float* on = out + (size_t)n * STATS_PER_N;
        float accs = 0.f;
        float s1loc[16];
#pragma unroll 1
        for (int i = 0; i < 16; ++i) {          // v1 (also caches s1 sums)
            const int idx = i * 256 + tid;
            float s1v = 0.f;
#pragma unroll
            for (int c = 0; c < CHUNKS; ++c)
                s1v += ld_agent(Pn + (size_t)c * STATS_PER_N + 64 + idx);
            s1loc[i] = s1v;
            const int k = idx >> 6, d = idx & 63;
            const float v = (s1v - mu[idx] * sm.f.s0f[k]) * rsqrtf(w[k] * cv[idx]);
            const float u = (v >= 0.f) ? sqrtf(v) : -sqrtf(-v);
            on[k * 129 + 1 + d] = u;
            accs = fmaf(u, u, accs);
        }
        if (tid < 64) {                          // v0
            const float wv2 = w[tid];
            const float v = (sm.f.s0f[tid] - (float)T_ * wv2) * rsqrtf(wv2);
            const float u = (v >= 0.f) ? sqrtf(v) : -sqrtf(-v);
            on[tid * 129] = u;
            accs = fmaf(u, u, accs);
        }
#pragma unroll 1
        for (int i = 0; i < 16; ++i) {          // v2
            const int idx = i * 256 + tid;
            float s2v = 0.f;
#pragma unroll
            for (int c = 0; c < CHUNKS; ++c)
                s2v += ld_agent(Pn + (size_t)c * STATS_PER_N + 4160 + idx);
            const int k = idx >> 6, d = idx & 63;
            const float m_ = mu[idx], c_ = cv[idx];
            const float v = (s2v - 2.f * m_ * s1loc[i] + (m_ * m_ - c_) * sm.f.s0f[k]) *
                            (rsqrtf(2.f * w[k]) / c_);
            const float u = (v >= 0.f) ? sqrtf(v) : -sqrtf(-v);
            on[k * 129 + 65 + d] = u;
            accs = fmaf(u, u, accs);
        }
        // block L2-norm reduce + scale
        float ss = accs;
#pragma unroll
        for (int off = 32; off > 0; off >>= 1) ss += __shfl_xor(ss, off, 64);
        if (lane == 0) sm.f.red[wv] = ss;
        __syncthreads();                          // also drains the u-stores
        const float rn = rsqrtf(sm.f.red[0] + sm.f.red[1] + sm.f.red[2] + sm.f.red[3]);
        for (int e = tid; e < STATS_PER_N; e += 256)
            on[e] *= rn;
    } else {
        // fallback: atomic accumulation into stats (small-ws path)
        float* sb = outbuf + (size_t)n * STATS_PER_N;
        if (tid < 64)
            atomicAdd(&sb[tid],
                      sm.m.s0sh[0][tid] + sm.m.s0sh[1][tid] + sm.m.s0sh[2][tid] + sm.m.s0sh[3][tid]);
        const int d = 32 * dh + (lane & 31);
        float* dst = sb + 64 + sig * 4096;
#pragma unroll
        for (int mt = 0; mt < 2; ++mt)
#pragma unroll
            for (int r = 0; r < 16; ++r) {
                const int kc = 32 * mt + (r & 3) + 8 * (r >> 2) + 4 * (lane >> 5);
                atomicAdd(&dst[kc * 64 + d], accB[mt][r]);
            }
    }
}

// ---------------------------------------------------------------------------
// fallback finalize (small-ws atomic path).
// ---------------------------------------------------------------------------
__global__ void fin_kernel(const float* __restrict__ w, const float* __restrict__ mu,
                           const float* __restrict__ cv, const float* __restrict__ stats,
                           float* __restrict__ out) {
    __shared__ float us[STATS_PER_N];
    __shared__ float red[4];
    const int n   = blockIdx.x;
    const int tid = threadIdx.x;
    const float* sb = stats + (size_t)n * STATS_PER_N;

    float ss = 0.f;
    if (tid < 64) {
        const float wv = w[tid];
        const float v = (sb[tid] - (float)T_ * wv) * rsqrtf(wv);
        const float u = (v >= 0.f) ? sqrtf(v) : -sqrtf(-v);
        us[tid * 129] = u;
        ss = fmaf(u, u, ss);
    }
#pragma unroll 1
    for (int i = 0; i < 16; ++i) {
        const int idx = i * 256 + tid;
        const int k = idx >> 6, d = idx & 63;
        const float v = (sb[64 + idx] - mu[idx] * sb[k]) * rsqrtf(w[k] * cv[idx]);
        const float u = (v >= 0.f) ? sqrtf(v) : -sqrtf(-v);
        us[k * 129 + 1 + d] = u;
        ss = fmaf(u, u, ss);
    }
#pragma unroll 1
    for (int i = 0; i < 16; ++i) {
        const int idx = i * 256 + tid;
        const int k = idx >> 6, d = idx & 63;
        const float m_ = mu[idx], c_ = cv[idx];
        const float s1v = sb[64 + idx], s2v = sb[64 + 4096 + idx];
        const float v = (s2v - 2.f * m_ * s1v + (m_ * m_ - c_) * sb[k]) *
                        (rsqrtf(2.f * w[k]) / c_);
        const float u = (v >= 0.f) ? sqrtf(v) : -sqrtf(-v);
        us[k * 129 + 65 + d] = u;
        ss = fmaf(u, u, ss);
    }
#pragma unroll
    for (int off = 32; off > 0; off >>= 1) ss += __shfl_xor(ss, off, 64);
    if ((tid & 63) == 0) red[tid >> 6] = ss;
    __syncthreads();
    const float tot = red[0] + red[1] + red[2] + red[3];
    const float rn = rsqrtf(tot);
    for (int e = tid; e < STATS_PER_N; e += 256)
        out[(size_t)n * STATS_PER_N + e] = us[e] * rn;
}

// ---------------------------------------------------------------------------
extern "C" void kernel_launch(void* const* d_in, const int* in_sizes, int n_in,
                              void* d_out, int out_size, void* d_ws, size_t ws_size,
                              hipStream_t stream) {
    const float* x  = (const float*)d_in[0];
    const float* w  = (const float*)d_in[1];
    const float* mu = (const float*)d_in[2];
    const float* cv = (const float*)d_in[3];
    float* out = (float*)d_out;

    const size_t part_elems = (size_t)CHUNKS * N_ * STATS_PER_N;   // 8.45M floats
    const size_t need_big = (part_elems + 32 + K_) * sizeof(float) +
                            (size_t)K_ * 128 * sizeof(half_t);

    if (ws_size >= need_big) {
        float* partials = (float*)d_ws;
        int*   flags = (int*)(partials + part_elems);
        float* Ap  = (float*)(flags + 32);
        half_t* WH = (half_t*)(Ap + K_);

        prep_kernel<<<9, 256, 0, stream>>>(w, mu, cv, Ap, WH, flags);
        main_kernel<<<dim3(CHUNKS, N_), 256, 0, stream>>>(x, Ap, WH, partials, out,
                                                          flags, w, mu, cv, 1);
    } else {
        const size_t stats_elems = (size_t)N_ * STATS_PER_N;
        float* stats = (float*)d_ws;
        int*   flags = (int*)(stats + stats_elems);
        float* Ap  = (float*)(flags + 32);
        half_t* WH = (half_t*)(Ap + K_);

        hipMemsetAsync(stats, 0, stats_elems * sizeof(float), stream);
        prep_kernel<<<9, 256, 0, stream>>>(w, mu, cv, Ap, WH, flags);
        main_kernel<<<dim3(CHUNKS, N_), 256, 0, stream>>>(x, Ap, WH, stats, out,
                                                          flags, w, mu, cv, 0);
        fin_kernel<<<N_, 256, 0, stream>>>(w, mu, cv, stats, out);
    }
}

// Round 10
// 158.442 us; speedup vs baseline: 2.0831x; 2.0831x over previous
//
#include <hip/hip_runtime.h>
#include <math.h>

#define N_  32
#define T_  8192
#define D_  64
#define K_  64
#define CHUNKS 32
#define TOK_PER_BLOCK (T_ / CHUNKS)    // 256
#define TB 64                          // tokens per batch
#define NBATCH (TOK_PER_BLOCK / TB)    // 4
#define STATS_PER_N (K_ + 2 * K_ * D_) // 8256
#define XSTR 72                        // f16 stride for Xs/Pt rows

typedef _Float16 half_t;
typedef __attribute__((ext_vector_type(8)))  _Float16 v8h;
typedef __attribute__((ext_vector_type(4)))  float    v4f;
typedef __attribute__((ext_vector_type(16))) float    v16f;

// ---------------------------------------------------------------------------
// prep (grid 9): blocks 0..7 pack WH (f16 MFMA A-frag order);
// block 8: Ap[k] = 2 log w - 0.5*sum_d(log c + mu^2/c), zero ssq[32].
// ---------------------------------------------------------------------------
__global__ void prep_kernel(const float* __restrict__ w, const float* __restrict__ mu,
                            const float* __restrict__ cv, float* __restrict__ Ap,
                            half_t* __restrict__ WH, float* __restrict__ ssq) {
    if (blockIdx.x < 8) {
#pragma unroll
        for (int i = 0; i < 4; ++i) {
            const int e = blockIdx.x * 1024 + i * 256 + threadIdx.x;  // 0..8191
            const int j = e & 7, l = (e >> 3) & 63, fs = e >> 9;
            const int tile = fs >> 2, s = fs & 3;
            const int kc = 16 * tile + (l & 15);
            const int f  = 32 * s + 8 * (l >> 4) + j;
            float val;
            if (f < 64) val = mu[kc * 64 + f] / cv[kc * 64 + f];
            else        val = -0.5f / cv[kc * 64 + (f - 64)];
            WH[e] = (half_t)val;
        }
    } else {
        if (threadIdx.x < 32) ssq[threadIdx.x] = 0.f;
        if (threadIdx.x < K_) {
            const int k = threadIdx.x;
            float acc = 0.f;
            for (int d = 0; d < D_; ++d) {
                const int idx = k * D_ + d;
                const float c = cv[idx], m = mu[idx];
                acc += logf(c) + m * m / c;
            }
            Ap[k] = 2.f * logf(w[k]) - 0.5f * acc;
        }
    }
}

// ---------------------------------------------------------------------------
// main: grid (32, 32) = 1024 blocks, block 256 (4 waves).
// Software pipeline with double-buffered Xs/Pt (Phase A never reads LDS):
//   A(0); { barrier; A(b+1) || B(b); } b=0..3
// -> 1 barrier/batch (5 total vs R8's 9). Qs dropped: Phase B's s2 waves
// square the gathered f16 in-register. LDS 37.9 KB -> 4 blocks/CU kept.
// Flush: plain coalesced partial-record stores (R8-proven; no atomics).
// ---------------------------------------------------------------------------
__launch_bounds__(256, 3)
__global__ void main_kernel(const float* __restrict__ x, const float* __restrict__ Ap,
                            const half_t* __restrict__ WH, float* __restrict__ outbuf,
                            int mode) {
    __shared__ half_t Xs[2][TB][XSTR];   // 18.0 KB
    __shared__ half_t Pt[2][K_][XSTR];   // 18.0 KB (transposed p: row=kc, col=token)
    __shared__ float  s0sh[4][64];       //  1.0 KB

    const int tid  = threadIdx.x;
    const int lane = tid & 63;
    const int wv   = tid >> 6;
    const int chunk = blockIdx.x;
    const int n     = blockIdx.y;
    const int q     = lane >> 4;
    const int c0    = lane & 15;
    const int tok   = 16 * wv + c0;   // this lane's token within the batch

    // resident weight A-frags
    v8h Wf[16];
#pragma unroll
    for (int t = 0; t < 4; ++t)
#pragma unroll
        for (int s = 0; s < 4; ++s)
            Wf[t * 4 + s] = *(const v8h*)(WH + (size_t)((t * 4 + s) * 64 + lane) * 8);

    float apv[16];
#pragma unroll
    for (int t = 0; t < 4; ++t)
#pragma unroll
        for (int r = 0; r < 4; ++r) apv[t * 4 + r] = Ap[16 * t + 4 * q + r];

    float S0loc[16];
#pragma unroll
    for (int j = 0; j < 16; ++j) S0loc[j] = 0.f;

    const int sig = wv >> 1;   // 0: s1 (B = x), 1: s2 (B = x^2, squared in-reg)
    const int dh  = wv & 1;    // d-half
    v16f accB[2];
#pragma unroll
    for (int m = 0; m < 2; ++m)
#pragma unroll
        for (int r = 0; r < 16; ++r) accB[m][r] = 0.f;

    const size_t xbase = ((size_t)n * T_ + (size_t)chunk * TOK_PER_BLOCK) * (size_t)D_;
    const float* xrow0 = x + xbase + tok * 64 + 8 * q;

    float4 R[4];
    R[0] = *(const float4*)(xrow0);
    R[1] = *(const float4*)(xrow0 + 4);
    R[2] = *(const float4*)(xrow0 + 32);
    R[3] = *(const float4*)(xrow0 + 36);

    // Phase A for batch i: frags from R (registers), stage Xs[i&1], prefetch
    // R(i+1), MFMA + softmax, write Pt[i&1]. Never reads LDS.
    auto phaseA = [&](int i) {
        const int buf = i & 1;
        v8h xh0, xh1, qh0, qh1;
        {
            const float4 a = R[0], b = R[1], c = R[2], d = R[3];
            xh0[0] = (half_t)a.x; xh0[1] = (half_t)a.y; xh0[2] = (half_t)a.z; xh0[3] = (half_t)a.w;
            xh0[4] = (half_t)b.x; xh0[5] = (half_t)b.y; xh0[6] = (half_t)b.z; xh0[7] = (half_t)b.w;
            xh1[0] = (half_t)c.x; xh1[1] = (half_t)c.y; xh1[2] = (half_t)c.z; xh1[3] = (half_t)c.w;
            xh1[4] = (half_t)d.x; xh1[5] = (half_t)d.y; xh1[6] = (half_t)d.z; xh1[7] = (half_t)d.w;
            qh0[0] = (half_t)(a.x * a.x); qh0[1] = (half_t)(a.y * a.y);
            qh0[2] = (half_t)(a.z * a.z); qh0[3] = (half_t)(a.w * a.w);
            qh0[4] = (half_t)(b.x * b.x); qh0[5] = (half_t)(b.y * b.y);
            qh0[6] = (half_t)(b.z * b.z); qh0[7] = (half_t)(b.w * b.w);
            qh1[0] = (half_t)(c.x * c.x); qh1[1] = (half_t)(c.y * c.y);
            qh1[2] = (half_t)(c.z * c.z); qh1[3] = (half_t)(c.w * c.w);
            qh1[4] = (half_t)(d.x * d.x); qh1[5] = (half_t)(d.y * d.y);
            qh1[6] = (half_t)(d.z * d.z); qh1[7] = (half_t)(d.w * d.w);
            *(v8h*)&Xs[buf][tok][8 * q]      = xh0;
            *(v8h*)&Xs[buf][tok][32 + 8 * q] = xh1;
        }
        if (i + 1 < NBATCH) {
            const float* xr = xrow0 + (size_t)(i + 1) * TB * D_;
            R[0] = *(const float4*)(xr);
            R[1] = *(const float4*)(xr + 4);
            R[2] = *(const float4*)(xr + 32);
            R[3] = *(const float4*)(xr + 36);
        }
        v4f acc[4];
#pragma unroll
        for (int t = 0; t < 4; ++t) acc[t] = (v4f)(0.f);
#pragma unroll
        for (int t = 0; t < 4; ++t) {
            acc[t] = __builtin_amdgcn_mfma_f32_16x16x32_f16(Wf[t * 4 + 0], xh0, acc[t], 0, 0, 0);
            acc[t] = __builtin_amdgcn_mfma_f32_16x16x32_f16(Wf[t * 4 + 1], xh1, acc[t], 0, 0, 0);
            acc[t] = __builtin_amdgcn_mfma_f32_16x16x32_f16(Wf[t * 4 + 2], qh0, acc[t], 0, 0, 0);
            acc[t] = __builtin_amdgcn_mfma_f32_16x16x32_f16(Wf[t * 4 + 3], qh1, acc[t], 0, 0, 0);
        }
        float pv[16];
        float m = -1e30f;
#pragma unroll
        for (int t = 0; t < 4; ++t)
#pragma unroll
            for (int r = 0; r < 4; ++r) {
                const float lg = acc[t][r] + apv[t * 4 + r];
                pv[t * 4 + r] = lg;
                m = fmaxf(m, lg);
            }
        m = fmaxf(m, __shfl_xor(m, 16, 64));
        m = fmaxf(m, __shfl_xor(m, 32, 64));
        float ssum = 0.f;
#pragma unroll
        for (int j = 0; j < 16; ++j) { pv[j] = __expf(pv[j] - m); ssum += pv[j]; }
        ssum += __shfl_xor(ssum, 16, 64);
        ssum += __shfl_xor(ssum, 32, 64);
        const float rs = 1.f / ssum;
#pragma unroll
        for (int j = 0; j < 16; ++j) { pv[j] *= rs; S0loc[j] += pv[j]; }
#pragma unroll
        for (int t = 0; t < 4; ++t)
#pragma unroll
            for (int r = 0; r < 4; ++r)
                Pt[buf][16 * t + 4 * q + r][tok] = (half_t)pv[t * 4 + r];
    };

    // Phase B for batch i: mfma 32x32x16 from Xs[i&1]/Pt[i&1].
    auto phaseB = [&](int i) {
        const int buf = i & 1;
        const int mm  = lane & 31;
        const int h   = lane >> 5;
        const int d   = 32 * dh + mm;
        const half_t* Arow0 = &Pt[buf][mm][0];
        const half_t* Arow1 = &Pt[buf][32 + mm][0];
#pragma unroll
        for (int st = 0; st < 4; ++st) {
            const int tB = 16 * st + 8 * h;
            const v8h a0 = *(const v8h*)(Arow0 + tB);
            const v8h a1 = *(const v8h*)(Arow1 + tB);
            v8h bf;
#pragma unroll
            for (int j = 0; j < 8; ++j)
                bf[j] = Xs[buf][tB + j][d];
            if (sig) bf = bf * bf;   // s2 operand: square in f16 (pk_mul)
            accB[0] = __builtin_amdgcn_mfma_f32_32x32x16_f16(a0, bf, accB[0], 0, 0, 0);
            accB[1] = __builtin_amdgcn_mfma_f32_32x32x16_f16(a1, bf, accB[1], 0, 0, 0);
        }
    };

    phaseA(0);
#pragma unroll 1
    for (int b = 0; b < NBATCH; ++b) {
        __syncthreads();                 // A(b) visible; B(b-1) done with buf (b+1)&1
        if (b + 1 < NBATCH) phaseA(b + 1);
        phaseB(b);
    }

    // -------- s0 block reduce + flush --------
#pragma unroll
    for (int j = 0; j < 16; ++j) {
        float v = S0loc[j];
        v += __shfl_xor(v, 1, 64);
        v += __shfl_xor(v, 2, 64);
        v += __shfl_xor(v, 4, 64);
        v += __shfl_xor(v, 8, 64);
        S0loc[j] = v;
    }
    if (c0 == 0) {
#pragma unroll
        for (int t = 0; t < 4; ++t)
#pragma unroll
            for (int r = 0; r < 4; ++r)
                s0sh[wv][16 * t + 4 * q + r] = S0loc[t * 4 + r];
    }
    __syncthreads();

    if (mode == 1) {
        float* dstb = outbuf + (size_t)(n * CHUNKS + chunk) * STATS_PER_N;
        if (tid < 64)
            dstb[tid] = s0sh[0][tid] + s0sh[1][tid] + s0sh[2][tid] + s0sh[3][tid];
        const int d = 32 * dh + (lane & 31);
        float* dst = dstb + 64 + sig * 4096;
#pragma unroll
        for (int mt = 0; mt < 2; ++mt)
#pragma unroll
            for (int r = 0; r < 16; ++r) {
                const int kc = 32 * mt + (r & 3) + 8 * (r >> 2) + 4 * (lane >> 5);
                dst[kc * 64 + d] = accB[mt][r];
            }
    } else {
        float* sb = outbuf + (size_t)n * STATS_PER_N;
        if (tid < 64)
            atomicAdd(&sb[tid], s0sh[0][tid] + s0sh[1][tid] + s0sh[2][tid] + s0sh[3][tid]);
        const int d = 32 * dh + (lane & 31);
        float* dst = sb + 64 + sig * 4096;
#pragma unroll
        for (int mt = 0; mt < 2; ++mt)
#pragma unroll
            for (int r = 0; r < 16; ++r) {
                const int kc = 32 * mt + (r & 3) + 8 * (r >> 2) + 4 * (lane >> 5);
                atomicAdd(&dst[kc * 64 + d], accB[mt][r]);
            }
    }
}

// ---------------------------------------------------------------------------
// reduce_pow (grid (33, N)): chunk-sum partials, v0/v1/v2 + signed sqrt,
// write us in OUTPUT order; one ssq atomic per block. (R8-proven)
// ---------------------------------------------------------------------------
__global__ void reduce_pow_kernel(const float* __restrict__ partials,
                                  const float* __restrict__ w, const float* __restrict__ mu,
                                  const float* __restrict__ cv,
                                  float* __restrict__ us, float* __restrict__ ssq) {
    __shared__ float red[4];
    const int e = blockIdx.x * 256 + threadIdx.x;
    const int n = blockIdx.y;
    float u = 0.f;
    if (e < STATS_PER_N) {
        const float* base = partials + (size_t)n * CHUNKS * STATS_PER_N;
        float sv = 0.f;
#pragma unroll 8
        for (int c = 0; c < CHUNKS; ++c) sv += base[(size_t)c * STATS_PER_N + e];
        float v; int oidx;
        if (e < 64) {
            const float wv = w[e];
            v = (sv - (float)T_ * wv) * rsqrtf(wv);
            oidx = e * 129;
        } else if (e < 64 + 4096) {
            const int idx = e - 64, k = idx >> 6, d = idx & 63;
            float s0v = 0.f;
#pragma unroll 8
            for (int c = 0; c < CHUNKS; ++c) s0v += base[(size_t)c * STATS_PER_N + k];
            v = (sv - mu[idx] * s0v) * rsqrtf(w[k] * cv[idx]);
            oidx = k * 129 + 1 + d;
        } else {
            const int idx = e - 4160, k = idx >> 6, d = idx & 63;
            float s0v = 0.f, s1v = 0.f;
#pragma unroll 4
            for (int c = 0; c < CHUNKS; ++c) {
                s0v += base[(size_t)c * STATS_PER_N + k];
                s1v += base[(size_t)c * STATS_PER_N + 64 + idx];
            }
            const float m_ = mu[idx], c_ = cv[idx];
            v = (sv - 2.f * m_ * s1v + (m_ * m_ - c_) * s0v) * (rsqrtf(2.f * w[k]) / c_);
            oidx = k * 129 + 65 + d;
        }
        u = (v >= 0.f) ? sqrtf(v) : -sqrtf(-v);
        us[(size_t)n * STATS_PER_N + oidx] = u;
    }
    float ss = u * u;
#pragma unroll
    for (int off = 32; off > 0; off >>= 1) ss += __shfl_xor(ss, off, 64);
    if ((threadIdx.x & 63) == 0) red[threadIdx.x >> 6] = ss;
    __syncthreads();
    if (threadIdx.x == 0)
        atomicAdd(&ssq[n], red[0] + red[1] + red[2] + red[3]);
}

// ---------------------------------------------------------------------------
// scale (grid (33, N)): out = us * rsqrt(ssq[n])
// ---------------------------------------------------------------------------
__global__ void scale_kernel(const float* __restrict__ us, const float* __restrict__ ssq,
                             float* __restrict__ out) {
    const int e = blockIdx.x * 256 + threadIdx.x;
    const int n = blockIdx.y;
    if (e < STATS_PER_N)
        out[(size_t)n * STATS_PER_N + e] = us[(size_t)n * STATS_PER_N + e] * rsqrtf(ssq[n]);
}

// ---------------------------------------------------------------------------
// fallback finalize (small-ws atomic path).
// ---------------------------------------------------------------------------
__global__ void fin_kernel(const float* __restrict__ w, const float* __restrict__ mu,
                           const float* __restrict__ cv, const float* __restrict__ stats,
                           float* __restrict__ out) {
    __shared__ float us[STATS_PER_N];
    __shared__ float red[4];
    const int n   = blockIdx.x;
    const int tid = threadIdx.x;
    const float* sb = stats + (size_t)n * STATS_PER_N;

    float ss = 0.f;
    if (tid < 64) {
        const float wv = w[tid];
        const float v = (sb[tid] - (float)T_ * wv) * rsqrtf(wv);
        const float u = (v >= 0.f) ? sqrtf(v) : -sqrtf(-v);
        us[tid * 129] = u;
        ss = fmaf(u, u, ss);
    }
#pragma unroll 1
    for (int i = 0; i < 16; ++i) {
        const int idx = i * 256 + tid;
        const int k = idx >> 6, d = idx & 63;
        const float v = (sb[64 + idx] - mu[idx] * sb[k]) * rsqrtf(w[k] * cv[idx]);
        const float u = (v >= 0.f) ? sqrtf(v) : -sqrtf(-v);
        us[k * 129 + 1 + d] = u;
        ss = fmaf(u, u, ss);
    }
#pragma unroll 1
    for (int i = 0; i < 16; ++i) {
        const int idx = i * 256 + tid;
        const int k = idx >> 6, d = idx & 63;
        const float m_ = mu[idx], c_ = cv[idx];
        const float s1v = sb[64 + idx], s2v = sb[64 + 4096 + idx];
        const float v = (s2v - 2.f * m_ * s1v + (m_ * m_ - c_) * sb[k]) *
                        (rsqrtf(2.f * w[k]) / c_);
        const float u = (v >= 0.f) ? sqrtf(v) : -sqrtf(-v);
        us[k * 129 + 65 + d] = u;
        ss = fmaf(u, u, ss);
    }
#pragma unroll
    for (int off = 32; off > 0; off >>= 1) ss += __shfl_xor(ss, off, 64);
    if ((tid & 63) == 0) red[tid >> 6] = ss;
    __syncthreads();
    const float tot = red[0] + red[1] + red[2] + red[3];
    const float rn = rsqrtf(tot);
    for (int e = tid; e < STATS_PER_N; e += 256)
        out[(size_t)n * STATS_PER_N + e] = us[e] * rn;
}

// ---------------------------------------------------------------------------
extern "C" void kernel_launch(void* const* d_in, const int* in_sizes, int n_in,
                              void* d_out, int out_size, void* d_ws, size_t ws_size,
                              hipStream_t stream) {
    const float* x  = (const float*)d_in[0];
    const float* w  = (const float*)d_in[1];
    const float* mu = (const float*)d_in[2];
    const float* cv = (const float*)d_in[3];
    float* out = (float*)d_out;

    const size_t part_elems = (size_t)CHUNKS * N_ * STATS_PER_N;   // 8.45M floats
    const size_t us_elems   = (size_t)N_ * STATS_PER_N;
    const size_t need_big = (part_elems + us_elems + 32 + K_ + (size_t)K_ * 64) * sizeof(float);

    if (ws_size >= need_big) {
        float* partials = (float*)d_ws;
        float* us  = partials + part_elems;
        float* ssq = us + us_elems;
        float* Ap  = ssq + 32;
        half_t* WH = (half_t*)(Ap + K_);

        prep_kernel<<<9, 256, 0, stream>>>(w, mu, cv, Ap, WH, ssq);
        main_kernel<<<dim3(CHUNKS, N_), 256, 0, stream>>>(x, Ap, WH, partials, 1);
        reduce_pow_kernel<<<dim3(33, N_), 256, 0, stream>>>(partials, w, mu, cv, us, ssq);
        scale_kernel<<<dim3(33, N_), 256, 0, stream>>>(us, ssq, out);
    } else {
        float* stats = (float*)d_ws;
        float* ssq = stats + us_elems;
        float* Ap  = ssq + 32;
        half_t* WH = (half_t*)(Ap + K_);

        hipMemsetAsync(stats, 0, us_elems * sizeof(float), stream);
        prep_kernel<<<9, 256, 0, stream>>>(w, mu, cv, Ap, WH, ssq);
        main_kernel<<<dim3(CHUNKS, N_), 256, 0, stream>>>(x, Ap, WH, stats, 0);
        fin_kernel<<<N_, 256, 0, stream>>>(w, mu, cv, stats, out);
    }
}